// Round 3
// baseline (886.250 us; speedup 1.0000x reference)
//
#include <hip/hip_runtime.h>
#include <math.h>

#define H 1024
#define V 50257
#define L 512
#define RPB 32                       // vocab rows per logits chunk
#define NPART ((V + RPB - 1) / RPB)  // 1571 chunks
#define GRID 786                     // blocks; 2 chunk-slots/block covers 1572
#define TOTW (GRID * 4)              // 3144 waves

__device__ inline float wave_reduce_sum(float v) {
    #pragma unroll
    for (int off = 32; off > 0; off >>= 1)
        v += __shfl_down(v, off, 64);
    return v;
}

__device__ inline float wave_reduce_max(float v) {
    #pragma unroll
    for (int off = 32; off > 0; off >>= 1)
        v = fmaxf(v, __shfl_down(v, off, 64));
    return v;
}

__device__ inline float dot4(float4 a, float4 b) {
    return a.x * b.x + a.y * b.y + a.z * b.z + a.w * b.w;
}

__device__ inline float sigmoidf_(float x) { return 1.f / (1.f + expf(-x)); }

// Manual grid barrier for a normal (non-cooperative) launch.
// Cumulative arrival count: barrier idx is complete when cnt == GRID*(idx+1).
// cnt/gen are zeroed by a hipMemsetAsync node before each kernel replay.
// All blocks are co-resident: __launch_bounds__(256,4) => >=4 blocks/CU =>
// capacity 1024 >= GRID=786. Bounded spin avoids a hard hang on surprise.
__device__ inline void gbar(unsigned* cnt, unsigned* gen, unsigned idx) {
    __syncthreads();
    if (threadIdx.x == 0) {
        __threadfence();                         // release: publish our stores
        unsigned old = atomicAdd(cnt, 1u);
        if (old == GRID * (idx + 1u) - 1u) {
            atomicExch(gen, idx + 1u);           // release the grid
        } else {
            int guard = 0;
            while (__atomic_load_n(gen, __ATOMIC_ACQUIRE) <= idx &&
                   ++guard < (1 << 24)) {
                __builtin_amdgcn_s_sleep(2);
            }
        }
        __threadfence();                         // acquire: invalidate stale lines
    }
    __syncthreads();
}

// One fused kernel, phases separated by manual grid barriers:
//  A: attention scores (512 rows) + gh = W_hh@h0+b_hh (3072 rows) + zero attnap
//  B: softmax(scores) [redundant, blocks 0..63] + attn_apply -> attnap (atomic)
//  C: gru_in = relu(comb_W @ [emb;attnap] + comb_b)   (1024 rows)
//  D: gx = W_ih @ gru_in + b_ih                       (3072 rows)
//  E: h_new (redundant per block) + logits GEMV (2 chunks/block, kept in LDS)
//  F: redundant LSE reduce of partials + final log-softmax write from LDS
__global__ __launch_bounds__(256, 4) void mega(
        const int* __restrict__ x,
        const float* __restrict__ enc,
        const float* __restrict__ hidden,
        const float* __restrict__ emb,
        const float* __restrict__ attn_W,
        const float* __restrict__ attn_b,
        const float* __restrict__ comb_W,
        const float* __restrict__ comb_b,
        const float* __restrict__ W_ih,
        const float* __restrict__ W_hh,
        const float* __restrict__ b_ih,
        const float* __restrict__ b_hh,
        const float* __restrict__ out_W,
        const float* __restrict__ out_b,
        float* __restrict__ out,
        float* __restrict__ ws) {
    float* scores   = ws;            // 512
    float* attnap   = ws + 512;      // 1024
    float* gru_in   = ws + 1536;     // 1024
    float* gx       = ws + 2560;     // 3072
    float* gh       = ws + 5632;     // 3072
    float* partials = ws + 8704;     // 2*NPART (3142)
    unsigned* cnt   = (unsigned*)(ws + 11904);
    unsigned* gen   = cnt + 1;

    const int t   = threadIdx.x;     // 256
    const int lid = t & 63, wid = t >> 6;
    const int gw  = blockIdx.x * 4 + wid;

    __shared__ float sh[H];          // h_new (phase E)
    __shared__ float sw[512];        // softmax weights (phase B)
    __shared__ float sl[64];         // this block's chunk logits (E -> F)
    __shared__ float smx[4], sms[4]; // small cross-wave reductions

    // ---------------- Phase A ----------------
    {
        const float4* hv = (const float4*)hidden;   // 256 f4
        for (int row = gw; row < 3584; row += TOTW) {
            if (row < 512) {
                const int xi = x[0];
                const float4* ev   = (const float4*)(emb + (size_t)xi * H);
                const float4* wrow = (const float4*)(attn_W + (size_t)row * (2 * H));
                float acc = 0.f;
                #pragma unroll
                for (int k = 0; k < 4; ++k) {
                    int idx = k * 64 + lid;
                    acc += dot4(ev[idx], wrow[idx]);
                }
                #pragma unroll
                for (int k = 0; k < 4; ++k) {
                    int idx = k * 64 + lid;
                    acc += dot4(hv[idx], wrow[256 + idx]);
                }
                acc = wave_reduce_sum(acc);
                if (lid == 0) scores[row] = acc + attn_b[row];
            } else {
                const int r = row - 512;
                const float4* wrow = (const float4*)(W_hh + (size_t)r * H);
                float acc = 0.f;
                #pragma unroll
                for (int k = 0; k < 4; ++k) {
                    int idx = k * 64 + lid;
                    acc += dot4(hv[idx], wrow[idx]);
                }
                acc = wave_reduce_sum(acc);
                if (lid == 0) gh[r] = acc + b_hh[r];
            }
        }
        if (blockIdx.x == GRID - 1)
            ((float4*)attnap)[t] = make_float4(0.f, 0.f, 0.f, 0.f);
    }
    gbar(cnt, gen, 0);

    // ---------------- Phase B (blocks 0..63) ----------------
    if (blockIdx.x < 64) {
        const int bx = blockIdx.x & 3, by = blockIdx.x >> 2;
        float v0 = scores[t], v1 = scores[t + 256];
        float m = wave_reduce_max(fmaxf(v0, v1));
        if (lid == 0) smx[wid] = m;
        __syncthreads();
        float M = fmaxf(fmaxf(smx[0], smx[1]), fmaxf(smx[2], smx[3]));
        float e0 = expf(v0 - M), e1 = expf(v1 - M);
        float s = wave_reduce_sum(e0 + e1);
        if (lid == 0) sms[wid] = s;
        __syncthreads();
        float S = sms[0] + sms[1] + sms[2] + sms[3];
        float w0 = e0 / S, w1 = e1 / S;
        sw[t] = w0;
        sw[t + 256] = w1;
        if (blockIdx.x == 0) {
            out[V + t] = w0;            // attention weights output
            out[V + t + 256] = w1;
        }
        __syncthreads();
        const int h  = bx * 256 + t;
        const int l0 = by * 32;
        float acc = 0.f;
        #pragma unroll 8
        for (int i = 0; i < 32; ++i)
            acc += sw[l0 + i] * enc[(size_t)(l0 + i) * H + h];
        atomicAdd(&attnap[h], acc);
    }
    gbar(cnt, gen, 1);

    // ---------------- Phase C (waves 0..1023) ----------------
    if (gw < 1024) {
        const int r = gw;
        const int xi = x[0];
        const float4* ev   = (const float4*)(emb + (size_t)xi * H);
        const float4* av   = (const float4*)attnap;
        const float4* wrow = (const float4*)(comb_W + (size_t)r * (2 * H));
        float acc = 0.f;
        #pragma unroll
        for (int k = 0; k < 4; ++k) {
            int idx = k * 64 + lid;
            acc += dot4(ev[idx], wrow[idx]);
        }
        #pragma unroll
        for (int k = 0; k < 4; ++k) {
            int idx = k * 64 + lid;
            acc += dot4(av[idx], wrow[256 + idx]);
        }
        acc = wave_reduce_sum(acc);
        if (lid == 0) gru_in[r] = fmaxf(acc + comb_b[r], 0.f);
    }
    gbar(cnt, gen, 2);

    // ---------------- Phase D (waves 0..3071) ----------------
    if (gw < 3072) {
        const int r = gw;
        const float4* vv   = (const float4*)gru_in;
        const float4* wrow = (const float4*)(W_ih + (size_t)r * H);
        float acc = 0.f;
        #pragma unroll
        for (int k = 0; k < 4; ++k) {
            int idx = k * 64 + lid;
            acc += dot4(vv[idx], wrow[idx]);
        }
        acc = wave_reduce_sum(acc);
        if (lid == 0) gx[r] = acc + b_ih[r];
    }
    gbar(cnt, gen, 3);

    // ---------------- Phase E: GRU elementwise (redundant) + logits ----------------
    {
        float4 xr = ((const float4*)gx)[t];
        float4 xz = ((const float4*)(gx + H))[t];
        float4 xn = ((const float4*)(gx + 2 * H))[t];
        float4 hr = ((const float4*)gh)[t];
        float4 hz = ((const float4*)(gh + H))[t];
        float4 hn = ((const float4*)(gh + 2 * H))[t];
        float4 h0 = ((const float4*)hidden)[t];
        float4 o;
        {
            float r = sigmoidf_(xr.x + hr.x), z = sigmoidf_(xz.x + hz.x);
            float n = tanhf(xn.x + r * hn.x);
            o.x = (1.f - z) * n + z * h0.x;
        }
        {
            float r = sigmoidf_(xr.y + hr.y), z = sigmoidf_(xz.y + hz.y);
            float n = tanhf(xn.y + r * hn.y);
            o.y = (1.f - z) * n + z * h0.y;
        }
        {
            float r = sigmoidf_(xr.z + hr.z), z = sigmoidf_(xz.z + hz.z);
            float n = tanhf(xn.z + r * hn.z);
            o.z = (1.f - z) * n + z * h0.z;
        }
        {
            float r = sigmoidf_(xr.w + hr.w), z = sigmoidf_(xz.w + hz.w);
            float n = tanhf(xn.w + r * hn.w);
            o.w = (1.f - z) * n + z * h0.w;
        }
        ((float4*)sh)[t] = o;
    }
    __syncthreads();
    {
        const float4* hv4 = (const float4*)sh;
        float4 hh0 = hv4[lid], hh1 = hv4[64 + lid], hh2 = hv4[128 + lid], hh3 = hv4[192 + lid];
        #pragma unroll 1
        for (int ci = 0; ci < 2; ++ci) {
            const int c = blockIdx.x + ci * GRID;
            if (c >= NPART) break;
            const int vbase = c * RPB + wid * 8;
            float acc[8];
            #pragma unroll
            for (int rr = 0; rr < 8; ++rr) {
                const int v = vbase + rr;             // wave-uniform
                if (v < V) {
                    const float4* wr = (const float4*)(out_W + (size_t)v * H);
                    acc[rr] = dot4(wr[lid], hh0) + dot4(wr[64 + lid], hh1)
                            + dot4(wr[128 + lid], hh2) + dot4(wr[192 + lid], hh3);
                } else {
                    acc[rr] = 0.f;
                }
            }
            #pragma unroll
            for (int rr = 0; rr < 8; ++rr) {
                float a = wave_reduce_sum(acc[rr]);
                if (lid == 0) {
                    const int v = vbase + rr;
                    sl[ci * 32 + wid * 8 + rr] = (v < V) ? (a + out_b[v]) : -INFINITY;
                }
            }
        }
    }
    __syncthreads();
    if (t == 0) {
        #pragma unroll 1
        for (int ci = 0; ci < 2; ++ci) {
            const int c = blockIdx.x + ci * GRID;
            if (c >= NPART) break;
            float M = -INFINITY;
            #pragma unroll
            for (int i = 0; i < 32; ++i) M = fmaxf(M, sl[ci * 32 + i]);
            float S = 0.f;
            #pragma unroll
            for (int i = 0; i < 32; ++i) S += expf(sl[ci * 32 + i] - M);
            partials[2 * c] = M;
            partials[2 * c + 1] = S;
        }
    }
    gbar(cnt, gen, 4);

    // ---------------- Phase F: redundant LSE + final write from LDS ----------------
    {
        float m = -INFINITY;
        for (int i = t; i < NPART; i += 256) m = fmaxf(m, partials[2 * i]);
        m = wave_reduce_max(m);
        if (lid == 0) smx[wid] = m;
        __syncthreads();
        float M = fmaxf(fmaxf(smx[0], smx[1]), fmaxf(smx[2], smx[3]));
        float s = 0.f;
        for (int i = t; i < NPART; i += 256)
            s += partials[2 * i + 1] * expf(partials[2 * i] - M);
        s = wave_reduce_sum(s);
        if (lid == 0) sms[wid] = s;
        __syncthreads();
        float S = sms[0] + sms[1] + sms[2] + sms[3];
        const float red = M + logf(S);
        if (t < 64) {
            const int ci = t >> 5;
            const int c = blockIdx.x + ci * GRID;
            if (c < NPART) {
                const int v = c * RPB + (t & 31);
                if (v < V) out[v] = sl[ci * 32 + (t & 31)] - red;
            }
        }
    }
}

extern "C" void kernel_launch(void* const* d_in, const int* in_sizes, int n_in,
                              void* d_out, int out_size, void* d_ws, size_t ws_size,
                              hipStream_t stream) {
    const int*   x       = (const int*)d_in[0];
    const float* enc     = (const float*)d_in[1];
    const float* hidden  = (const float*)d_in[2];
    const float* emb     = (const float*)d_in[3];
    const float* attn_W  = (const float*)d_in[4];
    const float* attn_b  = (const float*)d_in[5];
    const float* comb_W  = (const float*)d_in[6];
    const float* comb_b  = (const float*)d_in[7];
    const float* W_ih    = (const float*)d_in[8];
    const float* W_hh    = (const float*)d_in[9];
    const float* b_ih    = (const float*)d_in[10];
    const float* b_hh    = (const float*)d_in[11];
    const float* out_W   = (const float*)d_in[12];
    const float* out_b   = (const float*)d_in[13];
    float* out = (float*)d_out;
    float* ws  = (float*)d_ws;

    // zero the barrier state (cnt, gen) before each replay
    hipMemsetAsync(ws + 11904, 0, 2 * sizeof(unsigned), stream);

    mega<<<GRID, 256, 0, stream>>>(x, enc, hidden, emb, attn_W, attn_b,
                                   comb_W, comb_b, W_ih, W_hh, b_ih, b_hh,
                                   out_W, out_b, out, ws);
}